// Round 7
// baseline (16831.544 us; speedup 1.0000x reference)
//
#include <hip/hip_runtime.h>
#include <math.h>

// ---------------------------------------------------------------------------
// MGRU (BRITS-style) forward, bf16 MFMA — B-LOCAL persistent T-loop.
//   r6 post-mortem: barrier+sc1 persistent design is latency-bound at
//   ~70us/step (MfmaUtil 1%, occupancy 12.5%, serial AB->bar->C->bar chain).
//   Key fact: the recurrence is entirely b-row-local (x_hat, x_c, z_hat,
//   c_hat, GRU update each depend only on hid[b,:]).  So: 32 blocks x 16
//   b-rows, hidden state LDS-RESIDENT for all 128 steps (bf16 dbuf + f32
//   master), three block-local phases per step with __syncthreads only.
//   ZERO inter-block communication in the loop: no barriers, no atomics,
//   no sc1, no exchange buffers.  Weights (3.4MB/step/block) stream from
//   L2 (4 blocks/XCD share one copy).  Loss: per-(t,block) plain stores +
//   separate final2_k dispatch (r4/r6-proven mechanism).
// ---------------------------------------------------------------------------

#define F 256
#define H 512
#define B 512
#define T 128
#define TF 32768          // T*F
#define S3TF 98304        // 3*T*F
#define BTF ((size_t)B * T * F)

typedef __attribute__((ext_vector_type(8))) short bf8;
typedef __attribute__((ext_vector_type(4))) float f4;
#define MFMA16 __builtin_amdgcn_mfma_f32_16x16x32_bf16

__device__ inline short f2bf(float x) {
    unsigned u = __builtin_bit_cast(unsigned, x);
    u += 0x7fff + ((u >> 16) & 1);
    return (short)(u >> 16);
}
__device__ inline float bf2f(short s) {
    unsigned u = ((unsigned)(unsigned short)s) << 16;
    return __builtin_bit_cast(float, u);
}
__device__ inline float wsum(float v) {
#pragma unroll
    for (int o = 32; o > 0; o >>= 1) v += __shfl_down(v, o, 64);
    return v;
}

// ------------------------------------------------------- weight conversion
__global__ void wconv_k(const float* __restrict__ Wdx, const float* __restrict__ Wdh,
                        const float* __restrict__ Wz, const float* __restrict__ Wout,
                        const float* __restrict__ Wbeta, const float* __restrict__ Wih,
                        const float* __restrict__ Whh, short* __restrict__ wb) {
    int i = blockIdx.x * 256 + threadIdx.x;   // 2097152 total
    float v;
    if (i < 65536) v = Wdx[i];
    else if (i < 196608) v = Wdh[i - 65536];
    else if (i < 262144) { int l = i - 196608; v = ((l >> 8) == (l & 255)) ? 0.f : Wz[l]; }
    else if (i < 393216) v = Wout[i - 262144];
    else if (i < 524288) v = Wbeta[i - 393216];
    else if (i < 1310720) v = Wih[i - 524288];
    else v = Whh[i - 1310720];
    wb[i] = f2bf(v);
}

// --------------------------------------- activation conversion + den partials
__global__ void aconv_k(const float* __restrict__ inp, short* __restrict__ dbf,
                        short* __restrict__ abf, float* __restrict__ denP) {
    int i = blockIdx.x * 256 + threadIdx.x;   // 16777216 ; block = one (t,b) row
    int r = i >> 8, f = i & 255;
    int t = r >> 9, b = r & 511;
    const float* base = inp + (size_t)b * S3TF + (size_t)t * F;
    dbf[i] = f2bf(base[TF + f]);
    float m = base[2 * TF + f];
    abf[(size_t)r * 512 + 256 + f] = f2bf(m);   // m half of [gamma_x | m]
    float s = wsum(m);
    __shared__ float red[4];
    if ((threadIdx.x & 63) == 0) red[threadIdx.x >> 6] = s;
    __syncthreads();
    if (threadIdx.x == 0) denP[r] = red[0] + red[1] + red[2] + red[3];  // plain store
}

// ---------------------------------- precompute GEMMs (M=65536 rows, no LDS)
__global__ __launch_bounds__(256) void gx_gemm(const short* __restrict__ A,
                                               const short* __restrict__ W,
                                               const float* __restrict__ bias,
                                               short* __restrict__ abf) {
    int gw = blockIdx.x * 4 + (threadIdx.x >> 6);   // 65536 wave-tiles
    int lane = threadIdx.x & 63, l16 = lane & 15, quad = lane >> 4;
    int r0 = (gw >> 4) * 16, n0 = (gw & 15) * 16;
    const short* ar = A + (size_t)(r0 + l16) * 256 + quad * 8;
    const short* br = W + (size_t)(n0 + l16) * 256 + quad * 8;
    f4 acc = {};
#pragma unroll
    for (int k = 0; k < 256; k += 32)
        acc = MFMA16(*(const bf8*)(ar + k), *(const bf8*)(br + k), acc, 0, 0, 0);
    int n = n0 + l16;
    float bs = bias[n];
#pragma unroll
    for (int r = 0; r < 4; r++) {
        int row = r0 + quad * 4 + r;
        abf[(size_t)row * 512 + n] = f2bf(expf(-fmaxf(acc[r] + bs, 0.f)));
    }
}

__global__ __launch_bounds__(256) void gh_gemm(const short* __restrict__ A,
                                               const short* __restrict__ W,
                                               const float* __restrict__ bias,
                                               short* __restrict__ ghb) {
    int gw = blockIdx.x * 4 + (threadIdx.x >> 6);   // 131072 wave-tiles
    int lane = threadIdx.x & 63, l16 = lane & 15, quad = lane >> 4;
    int r0 = (gw >> 5) * 16, n0 = (gw & 31) * 16;
    const short* ar = A + (size_t)(r0 + l16) * 256 + quad * 8;
    const short* br = W + (size_t)(n0 + l16) * 256 + quad * 8;
    f4 acc = {};
#pragma unroll
    for (int k = 0; k < 256; k += 32)
        acc = MFMA16(*(const bf8*)(ar + k), *(const bf8*)(br + k), acc, 0, 0, 0);
    int n = n0 + l16;
    float bs = bias[n];
#pragma unroll
    for (int r = 0; r < 4; r++) {
        int row = r0 + quad * 4 + r;
        ghb[(size_t)row * 512 + n] = f2bf(expf(-fmaxf(acc[r] + bs, 0.f)));
    }
}

__global__ __launch_bounds__(256) void beta_gemm(const short* __restrict__ A,
                                                 const short* __restrict__ W,
                                                 const float* __restrict__ bias,
                                                 short* __restrict__ betab) {
    int gw = blockIdx.x * 4 + (threadIdx.x >> 6);   // 65536 wave-tiles, K=512
    int lane = threadIdx.x & 63, l16 = lane & 15, quad = lane >> 4;
    int r0 = (gw >> 4) * 16, n0 = (gw & 15) * 16;
    const short* ar = A + (size_t)(r0 + l16) * 512 + quad * 8;
    const short* br = W + (size_t)(n0 + l16) * 512 + quad * 8;
    f4 acc = {};
#pragma unroll
    for (int k = 0; k < 512; k += 32)
        acc = MFMA16(*(const bf8*)(ar + k), *(const bf8*)(br + k), acc, 0, 0, 0);
    int n = n0 + l16;
    float bs = bias[n];
#pragma unroll
    for (int r = 0; r < 4; r++) {
        int row = r0 + quad * 4 + r;
        betab[(size_t)row * 256 + n] = f2bf(acc[r] + bs);
    }
}

// ----------------------------------------------- b-local persistent T-loop
// 32 blocks x 512 threads (8 waves). Block bc owns b-rows [bc*16, bc*16+16).
// LDS: hidb[2] bf16 dbuf (32KB) + hidf f32 master (32KB) + xcs (8KB) +
//      gix [c_c|m] (16KB) = 88KB. All tiles XOR-swizzled (proven formula).
struct Loop2Args {
    const float* inp;
    const short* Woutb; const float* bout;
    const short* Wzmb;  const float* bz;
    const short* betab; const short* ghb;
    const short* Wihb;  const short* Whhb;
    const float* bih;   const float* bhh;
    float* out;
    float* lossP;                  // [T][32][3]
};

__global__ __launch_bounds__(512, 1) void loop2_k(Loop2Args P) {
    const int bc = blockIdx.x;
    const int tid = threadIdx.x;
    const int w = tid >> 6;            // 8 waves
    const int lane = tid & 63;
    const int l16 = lane & 15;
    const int quad = lane >> 4;
    const int b0 = bc * 16;

    __shared__ short hidb[2][16 * 512];   // bf16 hidden, double-buffered
    __shared__ short gix[16 * 512];       // [c_c | m]
    __shared__ short xcs[16 * 256];       // x_c
    __shared__ float hidf[16 * 512];      // f32 hidden master
    __shared__ float redl[3][8];

    for (int i = tid; i < 8192; i += 512) { hidb[0][i] = 0; hidf[i] = 0.f; }
    __syncthreads();

    int cur = 0;
#pragma unroll 1
    for (int t = 0; t < T; ++t) {
        // ============ phase 1: x_hat = hid @ Wout^T (N=256, K=512)
        float l1 = 0.f;
        f4 xhv[2], vv[2], mm[2];
#pragma unroll
        for (int s = 0; s < 2; ++s) {
            const int n0 = (w + 8 * s) * 16;
            f4 acc = {};
#pragma unroll
            for (int k = 0; k < 512; k += 32) {
                bf8 a = *(const bf8*)((const char*)hidb[cur] + (l16 << 10) +
                        (((unsigned)((k + quad * 8) * 2)) ^ ((l16 & 7) << 4)));
                const short* bp = P.Woutb + (size_t)(n0 + l16) * 512 + quad * 8 + k;
                acc = MFMA16(a, *(const bf8*)bp, acc, 0, 0, 0);
            }
            int n = n0 + l16;
            float bs = P.bout[n];
#pragma unroll
            for (int r = 0; r < 4; ++r) {
                int row = quad * 4 + r;
                const float* vb = P.inp + (size_t)(b0 + row) * S3TF + (size_t)t * F + n;
                float v = vb[0], m = vb[2 * TF];
                float xh = acc[r] + bs;
                l1 += fabsf(v - xh) * m;
                float xc = m * v + (1.f - m) * xh;
                *(short*)((char*)xcs + (row << 9) +
                          (((unsigned)(n * 2)) ^ ((row & 7) << 4))) = f2bf(xc);
                xhv[s][r] = xh; vv[s][r] = v; mm[s][r] = m;
            }
        }
        l1 = wsum(l1);
        if (lane == 0) redl[0][w] = l1;
        __syncthreads();

        // ============ phase 2: z_hat = x_c @ Wzm^T (N=256, K=256)
        float l2 = 0.f, l3 = 0.f;
#pragma unroll
        for (int s = 0; s < 2; ++s) {
            const int n0 = (w + 8 * s) * 16;
            f4 acc = {};
#pragma unroll
            for (int k = 0; k < 256; k += 32) {
                bf8 a = *(const bf8*)((char*)xcs + (l16 << 9) +
                        (((unsigned)((k + quad * 8) * 2)) ^ ((l16 & 7) << 4)));
                const short* bp = P.Wzmb + (size_t)(n0 + l16) * 256 + quad * 8 + k;
                acc = MFMA16(a, *(const bf8*)bp, acc, 0, 0, 0);
            }
            int n = n0 + l16;
            float bs = P.bz[n];
#pragma unroll
            for (int r = 0; r < 4; ++r) {
                int row = quad * 4 + r;
                int b = b0 + row;
                float zh = acc[r] + bs;
                float bt = bf2f(P.betab[((size_t)t * 512 + b) * 256 + n]);
                float xh = xhv[s][r];
                float ch = bt * zh + (1.f - bt) * xh;
                float m = mm[s][r], v = vv[s][r];
                float cc = m * v + (1.f - m) * ch;
                P.out[(size_t)b * TF + (size_t)t * F + n] = ch;
                P.out[BTF + (size_t)b * TF + (size_t)t * F + n] = cc;
                *(short*)((char*)gix + (row << 10) +
                          (((unsigned)(n * 2)) ^ ((row & 7) << 4))) = f2bf(cc);
                *(short*)((char*)gix + (row << 10) +
                          (((unsigned)((256 + n) * 2)) ^ ((row & 7) << 4))) = f2bf(m);
                l2 += fabsf(v - zh) * m;
                l3 += fabsf(v - ch) * m;
            }
        }
        l2 = wsum(l2); l3 = wsum(l3);
        if (lane == 0) { redl[1][w] = l2; redl[2][w] = l3; }
        __syncthreads();

        if (tid == 0) {                 // per-(t,block) loss partials, plain stores
            float a0 = 0.f, a1 = 0.f, a2 = 0.f;
            for (int q = 0; q < 8; ++q) { a0 += redl[0][q]; a1 += redl[1][q]; a2 += redl[2][q]; }
            float* lp = P.lossP + ((size_t)t * 32 + bc) * 3;
            lp[0] = a0; lp[1] = a1; lp[2] = a2;
        }

        // ============ phase 3: GRU, 6 families (N=512 j, K=512), 4 j-tiles/wave
        const int nxt = cur ^ 1;
#pragma unroll 1
        for (int s = 0; s < 4; ++s) {
            const int j0 = (w + 8 * s) * 16;
            f4 glr = {}, glz = {}, gln = {}, hlr = {}, hlz = {}, hln = {};
            const short* w0 = P.Wihb + (size_t)(j0 + l16) * 512 + quad * 8;
            const short* w3 = P.Whhb + (size_t)(j0 + l16) * 512 + quad * 8;
#pragma unroll
            for (int k = 0; k < 512; k += 32) {
                bf8 g = *(const bf8*)((char*)gix + (l16 << 10) +
                        (((unsigned)((k + quad * 8) * 2)) ^ ((l16 & 7) << 4)));
                bf8 h = *(const bf8*)((const char*)hidb[cur] + (l16 << 10) +
                        (((unsigned)((k + quad * 8) * 2)) ^ ((l16 & 7) << 4)));
                glr = MFMA16(g, *(const bf8*)(w0 + k), glr, 0, 0, 0);
                glz = MFMA16(g, *(const bf8*)(w0 + 512 * 512 + k), glz, 0, 0, 0);
                gln = MFMA16(g, *(const bf8*)(w0 + 1024 * 512 + k), gln, 0, 0, 0);
                hlr = MFMA16(h, *(const bf8*)(w3 + k), hlr, 0, 0, 0);
                hlz = MFMA16(h, *(const bf8*)(w3 + 512 * 512 + k), hlz, 0, 0, 0);
                hln = MFMA16(h, *(const bf8*)(w3 + 1024 * 512 + k), hln, 0, 0, 0);
            }
            int j = j0 + l16;
            float br_ = P.bih[j], bzg = P.bih[512 + j], bn_ = P.bih[1024 + j];
            float cr_ = P.bhh[j], czg = P.bhh[512 + j], cn_ = P.bhh[1024 + j];
#pragma unroll
            for (int r = 0; r < 4; ++r) {
                int row = quad * 4 + r;
                int b = b0 + row;
                float rg = 1.f / (1.f + expf(-(glr[r] + br_ + hlr[r] + cr_)));
                float zg = 1.f / (1.f + expf(-(glz[r] + bzg + hlz[r] + czg)));
                float ng = tanhf(gln[r] + bn_ + rg * (hln[r] + cn_));
                float hold = hidf[row * 512 + j];
                float hn = (1.f - zg) * ng + zg * hold;
                if (t + 1 < T) hn *= bf2f(P.ghb[((size_t)(t + 1) * 512 + b) * 512 + j]);
                hidf[row * 512 + j] = hn;
                *(short*)((char*)hidb[nxt] + (row << 10) +
                          (((unsigned)(j * 2)) ^ ((row & 7) << 4))) = f2bf(hn);
            }
        }
        __syncthreads();
        cur = nxt;
    }
}

// ------------------------- final loss (separate dispatch; r4/r6-proven)
__global__ void final2_k(const float* __restrict__ lossP,
                         const float* __restrict__ denP,
                         float* __restrict__ outloss) {
    int tid = threadIdx.x;   // 128, one per t
    float n = 0.f;
    for (int blk = 0; blk < 32; ++blk) {
        const float* lp = lossP + ((size_t)tid * 32 + blk) * 3;
        n += lp[0] + lp[1] + lp[2];
    }
    float d = 0.f;
    const float* dp = denP + (size_t)tid * 512;
    for (int b = 0; b < 512; ++b) d += dp[b];
    __shared__ float red[128];
    red[tid] = n / (d + 1e-5f);
    __syncthreads();
    for (int o = 64; o > 0; o >>= 1) { if (tid < o) red[tid] += red[tid + o]; __syncthreads(); }
    if (tid == 0) *outloss = red[0];
}

// ---------------------------------------------------------------------------
extern "C" void kernel_launch(void* const* d_in, const int* in_sizes, int n_in,
                              void* d_out, int out_size, void* d_ws, size_t ws_size,
                              hipStream_t stream) {
    const float* inp   = (const float*)d_in[0];
    const float* Wdx   = (const float*)d_in[1];
    const float* bdx   = (const float*)d_in[2];
    const float* Wdh   = (const float*)d_in[3];
    const float* bdh   = (const float*)d_in[4];
    const float* Wout  = (const float*)d_in[5];
    const float* bout  = (const float*)d_in[6];
    const float* Wz    = (const float*)d_in[7];
    const float* bz    = (const float*)d_in[8];
    const float* Wbeta = (const float*)d_in[9];
    const float* bbeta = (const float*)d_in[10];
    const float* Wih   = (const float*)d_in[11];
    const float* Whh   = (const float*)d_in[12];
    const float* bih   = (const float*)d_in[13];
    const float* bhh   = (const float*)d_in[14];
    float* out = (float*)d_out;

    char* p = (char*)d_ws;
    short* wb    = (short*)p; p += (size_t)2097152 * 2;      // all weights bf16
    short* dbf   = (short*)p; p += (size_t)16777216 * 2;     // delta bf16 [T*B,256]
    short* abf   = (short*)p; p += (size_t)33554432 * 2;     // [gamma_x | m] [T*B,512]
    short* ghb   = (short*)p; p += (size_t)33554432 * 2;     // gamma_h bf16 [T*B,512]
    short* betab = (short*)p; p += (size_t)16777216 * 2;     // beta bf16 [T*B,256]
    float* lossP = (float*)p; p += (size_t)12288 * 4;        // [T][32][3]
    float* denP  = (float*)p; p += (size_t)65536 * 4;        // [T*512]

    const short* Wdxb   = wb;
    const short* Wdhb   = wb + 65536;
    const short* Wzmb   = wb + 196608;
    const short* Woutb  = wb + 262144;
    const short* Wbetab = wb + 393216;
    const short* Wihb   = wb + 524288;
    const short* Whhb   = wb + 1310720;

    wconv_k<<<8192, 256, 0, stream>>>(Wdx, Wdh, Wz, Wout, Wbeta, Wih, Whh, wb);
    aconv_k<<<65536, 256, 0, stream>>>(inp, dbf, abf, denP);
    gx_gemm<<<16384, 256, 0, stream>>>(dbf, Wdxb, bdx, abf);
    gh_gemm<<<32768, 256, 0, stream>>>(dbf, Wdhb, bdh, ghb);
    beta_gemm<<<16384, 256, 0, stream>>>(abf, Wbetab, bbeta, betab);

    Loop2Args la;
    la.inp = inp; la.Woutb = Woutb; la.bout = bout;
    la.Wzmb = Wzmb; la.bz = bz;
    la.betab = betab; la.ghb = ghb;
    la.Wihb = Wihb; la.Whhb = Whhb; la.bih = bih; la.bhh = bhh;
    la.out = out; la.lossP = lossP;
    loop2_k<<<32, 512, 0, stream>>>(la);
    final2_k<<<1, 128, 0, stream>>>(lossP, denP, out + 2 * BTF);
}

// Round 8
// 6031.919 us; speedup vs baseline: 2.7904x; 2.7904x over previous
//
#include <hip/hip_runtime.h>
#include <math.h>

// ---------------------------------------------------------------------------
// MGRU forward, bf16 MFMA — GROUPED persistent T-loop (v3).
//   r7 post-mortem: 32-block b-local design = latency-bound 126us/step
//   (each CU re-reads 3.4MB weights/step from L2 with 2 waves/SIMD).
//   v3: 32 groups x 8 slots = 256 blocks (all CUs) x 1024 threads (16 waves,
//   4/SIMD). Group = 16 b-rows. Phases 1-2 (x_hat, z_hat; 384KB weights)
//   REPLICATED per block (no intra-step sync). Phase 3 (GRU, 3MB weights)
//   SPLIT 8x: each slot owns j-slice of 64. Per-block weights 768KB/step;
//   per-XCD L2 24.6MB/step ~ 5.7us.  Cross-block: ONLY the h-slice exchange,
//   once per step: 2KB sc1 store -> 8-block group barrier (r6-proven relaxed
//   atomic recipe) -> 16KB sc1 bulk reload into LDS. No sc1 inside K-loops.
//   Phase-3 per-wave split: (jt 0-3) x (ih/hh family) x (K half): 16 waves,
//   partials combined via LDS pp[]. Loss: slot-0 plain stores + final2_k.
// ---------------------------------------------------------------------------

#define F 256
#define H 512
#define B 512
#define T 128
#define TF 32768          // T*F
#define S3TF 98304        // 3*T*F
#define BTF ((size_t)B * T * F)

typedef __attribute__((ext_vector_type(8))) short bf8;
typedef __attribute__((ext_vector_type(4))) float f4;
typedef unsigned long long u64;
#define MFMA16 __builtin_amdgcn_mfma_f32_16x16x32_bf16

__device__ inline short f2bf(float x) {
    unsigned u = __builtin_bit_cast(unsigned, x);
    u += 0x7fff + ((u >> 16) & 1);
    return (short)(u >> 16);
}
__device__ inline float bf2f(short s) {
    unsigned u = ((unsigned)(unsigned short)s) << 16;
    return __builtin_bit_cast(float, u);
}
__device__ inline float wsum(float v) {
#pragma unroll
    for (int o = 32; o > 0; o >>= 1) v += __shfl_down(v, o, 64);
    return v;
}
__device__ inline u64 load8_coh(const u64* p) {
    return __hip_atomic_load(p, __ATOMIC_RELAXED, __HIP_MEMORY_SCOPE_AGENT);
}
__device__ inline void store8_coh(u64* p, u64 v) {
    __hip_atomic_store(p, v, __ATOMIC_RELAXED, __HIP_MEMORY_SCOPE_AGENT);
}

// ------------------------------------------- 8-participant group barrier
__device__ inline void gbar8(unsigned* cnt, unsigned* gen) {
    __syncthreads();   // drains this block's sc1 stores (vmcnt 0 before s_barrier)
    if (threadIdx.x == 0) {
        unsigned g = __hip_atomic_load(gen, __ATOMIC_RELAXED, __HIP_MEMORY_SCOPE_AGENT);
        unsigned a = __hip_atomic_fetch_add(cnt, 1u, __ATOMIC_RELAXED, __HIP_MEMORY_SCOPE_AGENT);
        if (a == 7u) {
            __hip_atomic_store(cnt, 0u, __ATOMIC_RELAXED, __HIP_MEMORY_SCOPE_AGENT);
            __hip_atomic_store(gen, g + 1u, __ATOMIC_RELAXED, __HIP_MEMORY_SCOPE_AGENT);
        } else {
            while (__hip_atomic_load(gen, __ATOMIC_RELAXED, __HIP_MEMORY_SCOPE_AGENT) == g)
                __builtin_amdgcn_s_sleep(1);
        }
    }
    __syncthreads();
}

// --------------------------------------------------------------------- init
__global__ void initbar_k(unsigned* __restrict__ bar) {
    bar[threadIdx.x] = 0u;   // 1024 covers 32 groups x 32 slots
}

// ------------------------------------------------------- weight conversion
__global__ void wconv_k(const float* __restrict__ Wdx, const float* __restrict__ Wdh,
                        const float* __restrict__ Wz, const float* __restrict__ Wout,
                        const float* __restrict__ Wbeta, const float* __restrict__ Wih,
                        const float* __restrict__ Whh, short* __restrict__ wb) {
    int i = blockIdx.x * 256 + threadIdx.x;   // 2097152 total
    float v;
    if (i < 65536) v = Wdx[i];
    else if (i < 196608) v = Wdh[i - 65536];
    else if (i < 262144) { int l = i - 196608; v = ((l >> 8) == (l & 255)) ? 0.f : Wz[l]; }
    else if (i < 393216) v = Wout[i - 262144];
    else if (i < 524288) v = Wbeta[i - 393216];
    else if (i < 1310720) v = Wih[i - 524288];
    else v = Whh[i - 1310720];
    wb[i] = f2bf(v);
}

// --------------------------------------- activation conversion + den partials
__global__ void aconv_k(const float* __restrict__ inp, short* __restrict__ dbf,
                        short* __restrict__ abf, float* __restrict__ denP) {
    int i = blockIdx.x * 256 + threadIdx.x;   // 16777216 ; block = one (t,b) row
    int r = i >> 8, f = i & 255;
    int t = r >> 9, b = r & 511;
    const float* base = inp + (size_t)b * S3TF + (size_t)t * F;
    dbf[i] = f2bf(base[TF + f]);
    float m = base[2 * TF + f];
    abf[(size_t)r * 512 + 256 + f] = f2bf(m);   // m half of [gamma_x | m]
    float s = wsum(m);
    __shared__ float red[4];
    if ((threadIdx.x & 63) == 0) red[threadIdx.x >> 6] = s;
    __syncthreads();
    if (threadIdx.x == 0) denP[r] = red[0] + red[1] + red[2] + red[3];
}

// ---------------------------------- precompute GEMMs (M=65536 rows, no LDS)
__global__ __launch_bounds__(256) void gx_gemm(const short* __restrict__ A,
                                               const short* __restrict__ W,
                                               const float* __restrict__ bias,
                                               short* __restrict__ abf) {
    int gw = blockIdx.x * 4 + (threadIdx.x >> 6);
    int lane = threadIdx.x & 63, l16 = lane & 15, quad = lane >> 4;
    int r0 = (gw >> 4) * 16, n0 = (gw & 15) * 16;
    const short* ar = A + (size_t)(r0 + l16) * 256 + quad * 8;
    const short* br = W + (size_t)(n0 + l16) * 256 + quad * 8;
    f4 acc = {};
#pragma unroll
    for (int k = 0; k < 256; k += 32)
        acc = MFMA16(*(const bf8*)(ar + k), *(const bf8*)(br + k), acc, 0, 0, 0);
    int n = n0 + l16;
    float bs = bias[n];
#pragma unroll
    for (int r = 0; r < 4; r++) {
        int row = r0 + quad * 4 + r;
        abf[(size_t)row * 512 + n] = f2bf(expf(-fmaxf(acc[r] + bs, 0.f)));
    }
}

__global__ __launch_bounds__(256) void gh_gemm(const short* __restrict__ A,
                                               const short* __restrict__ W,
                                               const float* __restrict__ bias,
                                               short* __restrict__ ghb) {
    int gw = blockIdx.x * 4 + (threadIdx.x >> 6);
    int lane = threadIdx.x & 63, l16 = lane & 15, quad = lane >> 4;
    int r0 = (gw >> 5) * 16, n0 = (gw & 31) * 16;
    const short* ar = A + (size_t)(r0 + l16) * 256 + quad * 8;
    const short* br = W + (size_t)(n0 + l16) * 256 + quad * 8;
    f4 acc = {};
#pragma unroll
    for (int k = 0; k < 256; k += 32)
        acc = MFMA16(*(const bf8*)(ar + k), *(const bf8*)(br + k), acc, 0, 0, 0);
    int n = n0 + l16;
    float bs = bias[n];
#pragma unroll
    for (int r = 0; r < 4; r++) {
        int row = r0 + quad * 4 + r;
        ghb[(size_t)row * 512 + n] = f2bf(expf(-fmaxf(acc[r] + bs, 0.f)));
    }
}

__global__ __launch_bounds__(256) void beta_gemm(const short* __restrict__ A,
                                                 const short* __restrict__ W,
                                                 const float* __restrict__ bias,
                                                 short* __restrict__ betab) {
    int gw = blockIdx.x * 4 + (threadIdx.x >> 6);
    int lane = threadIdx.x & 63, l16 = lane & 15, quad = lane >> 4;
    int r0 = (gw >> 4) * 16, n0 = (gw & 15) * 16;
    const short* ar = A + (size_t)(r0 + l16) * 512 + quad * 8;
    const short* br = W + (size_t)(n0 + l16) * 512 + quad * 8;
    f4 acc = {};
#pragma unroll
    for (int k = 0; k < 512; k += 32)
        acc = MFMA16(*(const bf8*)(ar + k), *(const bf8*)(br + k), acc, 0, 0, 0);
    int n = n0 + l16;
    float bs = bias[n];
#pragma unroll
    for (int r = 0; r < 4; r++) {
        int row = r0 + quad * 4 + r;
        betab[(size_t)row * 256 + n] = f2bf(acc[r] + bs);
    }
}

// ----------------------------------------------- grouped persistent T-loop
struct Loop3Args {
    const float* inp;
    const short* Woutb; const float* bout;
    const short* Wzmb;  const float* bz;
    const short* betab; const short* ghb;
    const short* Wihb;  const short* Whhb;
    const float* bih;   const float* bhh;
    float* out;
    float* lossP;                  // [T][32][3]
    short* hbE;                    // [2][512*512] h exchange (sc1)
    unsigned* bar;                 // 32 groups x 32 u32
};

__global__ __launch_bounds__(1024, 1) void loop3_k(Loop3Args P) {
    const int bc = blockIdx.x;
    const int g = bc >> 3, slot = bc & 7;
    const int tid = threadIdx.x;
    const int w = tid >> 6;            // 16 waves
    const int lane = tid & 63;
    const int l16 = lane & 15;
    const int quad = lane >> 4;
    const int b0 = g * 16;
    const int j00 = slot * 64;

    __shared__ short hidb[16 * 512];      // bf16 hidden (full), swizzled
    __shared__ short gix[16 * 512];       // [c_c | m], swizzled
    __shared__ short xcs[16 * 256];       // x_c, swizzled
    __shared__ short hslice[16 * 64];     // own h-slice staging
    __shared__ float hidf[16 * 64];       // f32 master, own slice only
    __shared__ float pp[4][3][3][16][17]; // phase-3 partials (padded)
    __shared__ float redl[3][16];

    for (int i = tid; i < 8192; i += 1024) hidb[i] = 0;
    if (tid < 1024) { if (tid < 1024) { } }
    for (int i = tid; i < 1024; i += 1024) hidf[i] = 0.f;
    __syncthreads();

    unsigned* cnt = P.bar + g * 32;
    unsigned* gen = cnt + 16;

#pragma unroll 1
    for (int t = 0; t < T; ++t) {
        // ============ phase 1: x_hat = hid @ Wout^T  (tile tt = w)
        const int n0 = w * 16;
        f4 acc1 = {};
#pragma unroll
        for (int k = 0; k < 512; k += 32) {
            bf8 a = *(const bf8*)((const char*)hidb + (l16 << 10) +
                    (((unsigned)((k + quad * 8) * 2)) ^ ((l16 & 7) << 4)));
            const short* bp = P.Woutb + (size_t)(n0 + l16) * 512 + quad * 8 + k;
            acc1 = MFMA16(a, *(const bf8*)bp, acc1, 0, 0, 0);
        }
        float l1 = 0.f;
        f4 xhv, vv, mm;
        {
            int n = n0 + l16;
            float bs = P.bout[n];
#pragma unroll
            for (int r = 0; r < 4; ++r) {
                int row = quad * 4 + r;
                const float* vb = P.inp + (size_t)(b0 + row) * S3TF + (size_t)t * F + n;
                float v = vb[0], m = vb[2 * TF];
                float xh = acc1[r] + bs;
                l1 += fabsf(v - xh) * m;
                float xc = m * v + (1.f - m) * xh;
                *(short*)((char*)xcs + (row << 9) +
                          (((unsigned)(n * 2)) ^ ((row & 7) << 4))) = f2bf(xc);
                xhv[r] = xh; vv[r] = v; mm[r] = m;
            }
        }
        l1 = wsum(l1);
        if (lane == 0) redl[0][w] = l1;
        __syncthreads();

        // ============ phase 2: z_hat = x_c @ Wzm^T  (tile tt = w, K=256)
        f4 acc2 = {};
#pragma unroll
        for (int k = 0; k < 256; k += 32) {
            bf8 a = *(const bf8*)((char*)xcs + (l16 << 9) +
                    (((unsigned)((k + quad * 8) * 2)) ^ ((l16 & 7) << 4)));
            const short* bp = P.Wzmb + (size_t)(n0 + l16) * 256 + quad * 8 + k;
            acc2 = MFMA16(a, *(const bf8*)bp, acc2, 0, 0, 0);
        }
        float l2 = 0.f, l3 = 0.f;
        {
            int n = n0 + l16;
            float bs = P.bz[n];
            bool ownout = ((w >> 1) == slot);   // slot's out-slice = cols [32*slot,32*slot+32)
#pragma unroll
            for (int r = 0; r < 4; ++r) {
                int row = quad * 4 + r, b = b0 + row;
                float zh = acc2[r] + bs;
                float bt = bf2f(P.betab[((size_t)t * 512 + b) * 256 + n]);
                float xh = xhv[r];
                float ch = bt * zh + (1.f - bt) * xh;
                float m = mm[r], v = vv[r];
                float cc = m * v + (1.f - m) * ch;
                if (ownout) {
                    P.out[(size_t)b * TF + (size_t)t * F + n] = ch;
                    P.out[BTF + (size_t)b * TF + (size_t)t * F + n] = cc;
                }
                *(short*)((char*)gix + (row << 10) +
                          (((unsigned)(n * 2)) ^ ((row & 7) << 4))) = f2bf(cc);
                *(short*)((char*)gix + (row << 10) +
                          (((unsigned)((256 + n) * 2)) ^ ((row & 7) << 4))) = f2bf(m);
                l2 += fabsf(v - zh) * m;
                l3 += fabsf(v - ch) * m;
            }
        }
        l2 = wsum(l2); l3 = wsum(l3);
        if (lane == 0) { redl[1][w] = l2; redl[2][w] = l3; }
        __syncthreads();

        if (slot == 0 && tid == 0) {    // group loss partials (replication-exact)
            float a0 = 0.f, a1 = 0.f, a2s = 0.f;
            for (int q = 0; q < 16; ++q) { a0 += redl[0][q]; a1 += redl[1][q]; a2s += redl[2][q]; }
            float* lp = P.lossP + ((size_t)t * 32 + g) * 3;
            lp[0] = a0; lp[1] = a1; lp[2] = a2s;
        }

        // ============ phase 3: GRU j-slice [j00, j00+64), 16-way wave split:
        // w -> (jt = w&3) x (rk = w>>2): rk0 ih/k-lo, rk1 ih/k-hi, rk2 hh/k-lo, rk3 hh/k-hi
        {
            const int jt = w & 3, rk = w >> 2;
            const int kbase = (rk & 1) * 256;
            const bool useg = (rk < 2);
            const short* wbase = useg ? P.Wihb : P.Whhb;
            const int jrow = j00 + jt * 16 + l16;
            f4 a0 = {}, a1 = {}, a2 = {};
            const short* wp0 = wbase + (size_t)jrow * 512 + quad * 8 + kbase;
#pragma unroll
            for (int kk = 0; kk < 256; kk += 32) {
                int k = kbase + kk;
                bf8 a = useg
                    ? *(const bf8*)((char*)gix + (l16 << 10) +
                        (((unsigned)((k + quad * 8) * 2)) ^ ((l16 & 7) << 4)))
                    : *(const bf8*)((const char*)hidb + (l16 << 10) +
                        (((unsigned)((k + quad * 8) * 2)) ^ ((l16 & 7) << 4)));
                a0 = MFMA16(a, *(const bf8*)(wp0 + kk), a0, 0, 0, 0);
                a1 = MFMA16(a, *(const bf8*)(wp0 + 512 * 512 + kk), a1, 0, 0, 0);
                a2 = MFMA16(a, *(const bf8*)(wp0 + 1024 * 512 + kk), a2, 0, 0, 0);
            }
            if (rk > 0) {
#pragma unroll
                for (int r = 0; r < 4; ++r) {
                    pp[jt][rk - 1][0][quad * 4 + r][l16] = a0[r];
                    pp[jt][rk - 1][1][quad * 4 + r][l16] = a1[r];
                    pp[jt][rk - 1][2][quad * 4 + r][l16] = a2[r];
                }
            }
            __syncthreads();
            if (rk == 0) {
                int j = j00 + jt * 16 + l16;
                float br_ = P.bih[j], bzg = P.bih[512 + j], bn_ = P.bih[1024 + j];
                float cr_ = P.bhh[j], czg = P.bhh[512 + j], cn_ = P.bhh[1024 + j];
#pragma unroll
                for (int r = 0; r < 4; ++r) {
                    int row = quad * 4 + r, b = b0 + row;
                    float ihr = a0[r] + pp[jt][0][0][row][l16];
                    float ihz = a1[r] + pp[jt][0][1][row][l16];
                    float ihn = a2[r] + pp[jt][0][2][row][l16];
                    float hhr = pp[jt][1][0][row][l16] + pp[jt][2][0][row][l16];
                    float hhz = pp[jt][1][1][row][l16] + pp[jt][2][1][row][l16];
                    float hhn = pp[jt][1][2][row][l16] + pp[jt][2][2][row][l16];
                    float rg = 1.f / (1.f + expf(-(ihr + br_ + hhr + cr_)));
                    float zg = 1.f / (1.f + expf(-(ihz + bzg + hhz + czg)));
                    float ng = tanhf(ihn + bn_ + rg * (hhn + cn_));
                    float hold = hidf[row * 64 + jt * 16 + l16];
                    float hn = (1.f - zg) * ng + zg * hold;
                    if (t + 1 < T) hn *= bf2f(P.ghb[((size_t)(t + 1) * 512 + b) * 512 + j]);
                    hidf[row * 64 + jt * 16 + l16] = hn;
                    hslice[row * 64 + jt * 16 + l16] = f2bf(hn);
                }
            }
        }

        // ============ tail: exchange h-slices (skip at last step)
        if (t + 1 < T) {
            __syncthreads();                       // hslice complete; hidb reads done
            const int par = (t + 1) & 1;
            u64* dst = (u64*)(P.hbE + (size_t)par * 262144);
            if (tid < 256) {
                int row = tid >> 4, ju = tid & 15;
                store8_coh(dst + (((size_t)(b0 + row) * 512 + j00) >> 2) + ju,
                           ((const u64*)hslice)[tid]);
            }
            gbar8(cnt, gen);                       // drains stores, syncs 8 slots
            const u64* srcp = (const u64*)(P.hbE + (size_t)par * 262144);
            int row = tid >> 6, c0 = tid & 63;
#pragma unroll
            for (int q = 0; q < 2; ++q) {
                int cu = c0 + 64 * q;
                u64 v = load8_coh(srcp + (((size_t)(b0 + row) * 512) >> 2) + cu);
                *(u64*)((char*)hidb + (row << 10) +
                        (((unsigned)(cu * 8)) ^ ((row & 7) << 4))) = v;
            }
            __syncthreads();
        }
    }
}

// ------------------------- final loss (separate dispatch; r4/r6-proven)
__global__ void final2_k(const float* __restrict__ lossP,
                         const float* __restrict__ denP,
                         float* __restrict__ outloss) {
    int tid = threadIdx.x;   // 128, one per t
    float n = 0.f;
    for (int blk = 0; blk < 32; ++blk) {
        const float* lp = lossP + ((size_t)tid * 32 + blk) * 3;
        n += lp[0] + lp[1] + lp[2];
    }
    float d = 0.f;
    const float* dp = denP + (size_t)tid * 512;
    for (int b = 0; b < 512; ++b) d += dp[b];
    __shared__ float red[128];
    red[tid] = n / (d + 1e-5f);
    __syncthreads();
    for (int o = 64; o > 0; o >>= 1) { if (tid < o) red[tid] += red[tid + o]; __syncthreads(); }
    if (tid == 0) *outloss = red[0];
}

// ---------------------------------------------------------------------------
extern "C" void kernel_launch(void* const* d_in, const int* in_sizes, int n_in,
                              void* d_out, int out_size, void* d_ws, size_t ws_size,
                              hipStream_t stream) {
    const float* inp   = (const float*)d_in[0];
    const float* Wdx   = (const float*)d_in[1];
    const float* bdx   = (const float*)d_in[2];
    const float* Wdh   = (const float*)d_in[3];
    const float* bdh   = (const float*)d_in[4];
    const float* Wout  = (const float*)d_in[5];
    const float* bout  = (const float*)d_in[6];
    const float* Wz    = (const float*)d_in[7];
    const float* bz    = (const float*)d_in[8];
    const float* Wbeta = (const float*)d_in[9];
    const float* bbeta = (const float*)d_in[10];
    const float* Wih   = (const float*)d_in[11];
    const float* Whh   = (const float*)d_in[12];
    const float* bih   = (const float*)d_in[13];
    const float* bhh   = (const float*)d_in[14];
    float* out = (float*)d_out;

    char* p = (char*)d_ws;
    short* wb    = (short*)p; p += (size_t)2097152 * 2;      // all weights bf16
    short* dbf   = (short*)p; p += (size_t)16777216 * 2;     // delta bf16 [T*B,256]
    short* abf   = (short*)p; p += (size_t)33554432 * 2;     // [gamma_x | m] [T*B,512]
    short* ghb   = (short*)p; p += (size_t)33554432 * 2;     // gamma_h bf16 [T*B,512]
    short* betab = (short*)p; p += (size_t)16777216 * 2;     // beta bf16 [T*B,256]
    float* lossP = (float*)p; p += (size_t)12288 * 4;        // [T][32][3]
    float* denP  = (float*)p; p += (size_t)65536 * 4;        // [T*512]
    short* hbE   = (short*)p; p += (size_t)524288 * 2;       // [2][512*512] exchange
    unsigned* bar = (unsigned*)p; p += (size_t)1024 * 4;     // 32 groups x 32

    const short* Wdxb   = wb;
    const short* Wdhb   = wb + 65536;
    const short* Wzmb   = wb + 196608;
    const short* Woutb  = wb + 262144;
    const short* Wbetab = wb + 393216;
    const short* Wihb   = wb + 524288;
    const short* Whhb   = wb + 1310720;

    wconv_k<<<8192, 256, 0, stream>>>(Wdx, Wdh, Wz, Wout, Wbeta, Wih, Whh, wb);
    aconv_k<<<65536, 256, 0, stream>>>(inp, dbf, abf, denP);
    gx_gemm<<<16384, 256, 0, stream>>>(dbf, Wdxb, bdx, abf);
    gh_gemm<<<32768, 256, 0, stream>>>(dbf, Wdhb, bdh, ghb);
    beta_gemm<<<16384, 256, 0, stream>>>(abf, Wbetab, bbeta, betab);
    initbar_k<<<1, 1024, 0, stream>>>(bar);

    Loop3Args la;
    la.inp = inp; la.Woutb = Woutb; la.bout = bout;
    la.Wzmb = Wzmb; la.bz = bz;
    la.betab = betab; la.ghb = ghb;
    la.Wihb = Wihb; la.Whhb = Whhb; la.bih = bih; la.bhh = bhh;
    la.out = out; la.lossP = lossP; la.hbE = hbE; la.bar = bar;
    loop3_k<<<256, 1024, 0, stream>>>(la);
    final2_k<<<1, 128, 0, stream>>>(lossP, denP, out + 2 * BTF);
}